// Round 1
// baseline (208.793 us; speedup 1.0000x reference)
//
#include <hip/hip_runtime.h>
#include <hip/hip_bf16.h>

// GegenbauerKAN layer as a fused BF16-MFMA GEMM.
// y[b,o] = sum_{i,d} C_d(tanh(x[b,i])) * coeffs[i,o,d]
//   => GEMM: M=16384(batch) x N=512(out) x K=4096(i*8+d)
// ALPHA=1 => recurrence collapses to Chebyshev-U: C_{n+1} = 2t*C_n - C_{n-1}.
// A-operand (G matrix) is generated on the fly from x inside A-tile staging.

#define I_DIM 512
#define O_DIM 512
#define NDEG 8            // DEGREE+1
#define BM 256
#define BN 128
#define BK 64             // 8 i-values per K-iteration
#define IPB 8             // i per iter
#define LSTR 72           // LDS row stride (bf16 elems): 144 B, 16B-aligned, depads banks
#define KITERS (I_DIM / IPB)   // 64

typedef __attribute__((ext_vector_type(8))) short s8v;    // 8 bf16 = 4 VGPRs (MFMA A/B frag)
typedef __attribute__((ext_vector_type(4))) float f32x4;  // MFMA C/D frag

__device__ __forceinline__ unsigned short f2bf(float f) {
    // round-to-nearest-even fp32 -> bf16 (inputs are finite, no NaN handling needed)
    unsigned int u = __float_as_uint(f);
    u += 0x7fffu + ((u >> 16) & 1u);
    return (unsigned short)(u >> 16);
}

__device__ __forceinline__ float fast_tanh(float v) {
    // tanh(v) = 1 - 2/(exp(2v)+1); v_exp + v_rcp, ~2-3 ulp, amplification by
    // dU7/dt <= 168 keeps poly error ~1e-5 absolute -- far below bf16 rounding.
    float e = __expf(v + v);
    float r = __builtin_amdgcn_rcpf(e + 1.0f);
    return 1.0f - (r + r);
}

extern "C" __global__ __launch_bounds__(512, 2)
void gegen_gemm(const float* __restrict__ x,
                const float* __restrict__ cf,
                float* __restrict__ out)
{
    __shared__ unsigned short As[BM * LSTR];   // A-tile, [m][k] bf16
    __shared__ unsigned short Ws[BN * LSTR];   // W-tile, [n][k] bf16 (transposed for b128 frag reads)

    const int tid  = threadIdx.x;
    const int lane = tid & 63;
    const int wave = tid >> 6;            // 0..7, grid 4x2 of 64x64 wave tiles
    const int fm   = lane & 15;           // MFMA row/col-within-16 index
    const int fq   = lane >> 4;           // quad 0..3
    const int wr   = (wave >> 1) << 6;    // wave row offset: 0,64,128,192
    const int wc   = (wave & 1) << 6;     // wave col offset: 0,64

    const int bm0 = blockIdx.y * BM;
    const int bn0 = blockIdx.x * BN;

    // ---- A staging map: 256 rows x 8 i = 2048 floats = 512 float4, one per thread
    const int ar = tid >> 1;              // row 0..255
    const int ai = (tid & 1) << 2;        // i_local 0 or 4
    const float* xp = x + (size_t)(bm0 + ar) * I_DIM + ai;

    // ---- W staging map: 8 i x 128 o pairs, 2 per thread (jj=0,1); each pair = 32 B coalesced
    const int w_il = tid >> 7;            // 0..3 (+4 for jj=1)
    const int w_ol = tid & 127;
    const float* wp = cf + ((size_t)w_il * O_DIM + bn0 + w_ol) * NDEG;

    f32x4 acc[4][4];
#pragma unroll
    for (int a = 0; a < 4; ++a)
#pragma unroll
        for (int b = 0; b < 4; ++b)
            acc[a][b] = (f32x4){0.0f, 0.0f, 0.0f, 0.0f};

    for (int it = 0; it < KITERS; ++it) {
        // ======== stage A: load x, tanh, Chebyshev-U chain, cvt, LDS b128 store ========
        const float4 xv = *reinterpret_cast<const float4*>(xp + it * IPB);
        const float vv[4] = {xv.x, xv.y, xv.z, xv.w};
#pragma unroll
        for (int j = 0; j < 4; ++j) {
            const float t  = fast_tanh(vv[j]);
            const float t2 = t + t;
            const float c1 = t2;
            const float c2 = t2 * c1 - 1.0f;
            const float c3 = t2 * c2 - c1;
            const float c4 = t2 * c3 - c2;
            const float c5 = t2 * c4 - c3;
            const float c6 = t2 * c5 - c4;
            const float c7 = t2 * c6 - c5;
            union { s8v s; unsigned short u[8]; } pk;
            pk.u[0] = 0x3f80u;            // bf16(1.0) = C_0
            pk.u[1] = f2bf(c1); pk.u[2] = f2bf(c2); pk.u[3] = f2bf(c3);
            pk.u[4] = f2bf(c4); pk.u[5] = f2bf(c5); pk.u[6] = f2bf(c6);
            pk.u[7] = f2bf(c7);
            *reinterpret_cast<s8v*>(&As[ar * LSTR + (ai + j) * NDEG]) = pk.s;
        }

        // ======== stage W: coeffs[i][o][0:8] (32 B contiguous) -> Ws[o][i*8+d] ========
#pragma unroll
        for (int jj = 0; jj < 2; ++jj) {
            const float* wsrc = wp + (size_t)it * (IPB * O_DIM * NDEG)
                                   + (size_t)jj * (4 * O_DIM * NDEG);
            const float4 w0 = reinterpret_cast<const float4*>(wsrc)[0];
            const float4 w1 = reinterpret_cast<const float4*>(wsrc)[1];
            union { s8v s; unsigned short u[8]; } pk;
            pk.u[0] = f2bf(w0.x); pk.u[1] = f2bf(w0.y);
            pk.u[2] = f2bf(w0.z); pk.u[3] = f2bf(w0.w);
            pk.u[4] = f2bf(w1.x); pk.u[5] = f2bf(w1.y);
            pk.u[6] = f2bf(w1.z); pk.u[7] = f2bf(w1.w);
            *reinterpret_cast<s8v*>(&Ws[w_ol * LSTR + (w_il + 4 * jj) * NDEG]) = pk.s;
        }
        __syncthreads();

        // ======== compute: 2 k-chunks of 32, 4x4 tiles of 16x16x32 MFMA ========
#pragma unroll
        for (int kc = 0; kc < 2; ++kc) {
            const int ka = kc * 32 + fq * 8;
            s8v afr[4], bfr[4];
#pragma unroll
            for (int tm = 0; tm < 4; ++tm)
                afr[tm] = *reinterpret_cast<const s8v*>(&As[(wr + tm * 16 + fm) * LSTR + ka]);
#pragma unroll
            for (int tn = 0; tn < 4; ++tn)
                bfr[tn] = *reinterpret_cast<const s8v*>(&Ws[(wc + tn * 16 + fm) * LSTR + ka]);
#pragma unroll
            for (int tm = 0; tm < 4; ++tm)
#pragma unroll
                for (int tn = 0; tn < 4; ++tn)
                    acc[tm][tn] = __builtin_amdgcn_mfma_f32_16x16x32_bf16(
                        afr[tm], bfr[tn], acc[tm][tn], 0, 0, 0);
        }
        __syncthreads();
    }

    // ======== epilogue: C/D layout col=lane&15, row=quad*4+reg ========
#pragma unroll
    for (int tm = 0; tm < 4; ++tm) {
#pragma unroll
        for (int tn = 0; tn < 4; ++tn) {
            const int row = bm0 + wr + tm * 16 + fq * 4;
            const int col = bn0 + wc + tn * 16 + fm;
#pragma unroll
            for (int r = 0; r < 4; ++r)
                out[(size_t)(row + r) * O_DIM + col] = acc[tm][tn][r];
        }
    }
}

extern "C" void kernel_launch(void* const* d_in, const int* in_sizes, int n_in,
                              void* d_out, int out_size, void* d_ws, size_t ws_size,
                              hipStream_t stream) {
    const float* x  = (const float*)d_in[0];
    const float* cf = (const float*)d_in[1];
    float* out = (float*)d_out;
    const int M = in_sizes[0] / I_DIM;       // 16384
    dim3 grid(O_DIM / BN, M / BM);           // (4, 64) = 256 blocks -> 1/CU
    gegen_gemm<<<grid, dim3(512, 1, 1), 0, stream>>>(x, cf, out);
}

// Round 2
// 172.399 us; speedup vs baseline: 1.2111x; 1.2111x over previous
//
#include <hip/hip_runtime.h>
#include <hip/hip_bf16.h>

// GegenbauerKAN layer == fused BF16-MFMA GEMM, M=16384 N=512 K=4096 (i*8+d).
// ALPHA=1 => Chebyshev-U recurrence: C_{n+1} = 2t*C_n - C_{n-1}, t = tanh(x).
// R2: 512 blocks (BM=128,BN=128, 256 thr) for 3-4 blocks/CU overlap;
//     coeffs pre-converted to bf16 in d_ws, W staged via global_load_lds(16B).

#define I_DIM 512
#define O_DIM 512
#define NDEG 8
#define BM 128
#define BN 128
#define IPB 8              // i-values per K-iteration (BK = 64)
#define LSTR 72            // As row stride in bf16 elems (144 B, banks balanced)
#define KITERS (I_DIM / IPB)
#define NTHREADS 256
#define W_ELEMS (I_DIM * O_DIM * NDEG)   // 2,097,152

typedef __attribute__((ext_vector_type(8))) short s8v;    // MFMA A/B frag (8 bf16)
typedef __attribute__((ext_vector_type(4))) float f32x4;  // MFMA C/D frag
typedef unsigned short u16;

__device__ __forceinline__ unsigned pack2bf(float a, float b) {
    // RNE fp32->bf16 for both, packed (a in low half, b in high half)
    unsigned ua = __float_as_uint(a), ub = __float_as_uint(b);
    ua += 0x7fffu + ((ua >> 16) & 1u);
    ub += 0x7fffu + ((ub >> 16) & 1u);
    return (ua >> 16) | (ub & 0xffff0000u);
}

__device__ __forceinline__ float fast_tanh(float v) {
    float e = __expf(v + v);
    float r = __builtin_amdgcn_rcpf(e + 1.0f);
    return 1.0f - (r + r);
}

// ---- one-shot coeffs fp32 -> bf16 into workspace (re-run every call; ws is re-poisoned)
extern "C" __global__ __launch_bounds__(256)
void cvt_w(const float* __restrict__ cf, u16* __restrict__ wbf) {
    const size_t idx = ((size_t)blockIdx.x * 256 + threadIdx.x) * 4;
    const float4 v = *reinterpret_cast<const float4*>(cf + idx);
    unsigned* dst = reinterpret_cast<unsigned*>(wbf + idx);
    dst[0] = pack2bf(v.x, v.y);
    dst[1] = pack2bf(v.z, v.w);
}

template <bool PRECONV>
__global__ __launch_bounds__(NTHREADS, 4)
void gegen_gemm(const float* __restrict__ x,
                const float* __restrict__ cf,
                const u16* __restrict__ wbf,
                float* __restrict__ out)
{
    __shared__ u16 As[BM * LSTR];          // [m][k] bf16, padded rows
    __shared__ u16 Ws[IPB * BN * NDEG];    // [i_local][o][d] bf16, UNPADDED (global_load_lds dst)

    const int tid  = threadIdx.x;
    const int lane = tid & 63;
    const int wave = tid >> 6;             // 0..3, 2x2 grid of 64x64 wave tiles
    const int fm   = lane & 15;
    const int fq   = lane >> 4;
    const int wr   = (wave >> 1) << 6;     // 0 / 64
    const int wc   = (wave & 1) << 6;      // 0 / 64

    const int bm0 = blockIdx.y * BM;
    const int bn0 = blockIdx.x * BN;

    // A staging map: 128 rows x 8 i = 256 float4, one per thread
    const int ar = tid >> 1;               // row 0..127
    const int ai = (tid & 1) << 2;         // i_local 0 or 4
    const float* xp = x + (size_t)(bm0 + ar) * I_DIM + ai;

    f32x4 acc[4][4];
#pragma unroll
    for (int a = 0; a < 4; ++a)
#pragma unroll
        for (int b = 0; b < 4; ++b)
            acc[a][b] = (f32x4){0.0f, 0.0f, 0.0f, 0.0f};

    for (int it = 0; it < KITERS; ++it) {
        // ---- W stage ----
        if (PRECONV) {
            // 16 KiB tile = 16 wave-chunks of 1 KiB; 4 chunks per wave.
            const u16* wsrc = wbf + ((size_t)(it * IPB) * O_DIM + bn0) * NDEG;
#pragma unroll
            for (int q = 0; q < 4; ++q) {
                const int c    = wave * 4 + q;   // 0..15
                const int il   = c >> 1;
                const int half = c & 1;
                const u16* src = wsrc + ((size_t)il * O_DIM + half * 64 + lane) * NDEG;
                u16* dst = &Ws[(il * BN + half * 64) * NDEG];  // wave-uniform base
                __builtin_amdgcn_global_load_lds(
                    (const __attribute__((address_space(1))) void*)src,
                    (__attribute__((address_space(3))) void*)dst, 16, 0, 0);
            }
        } else {
            // fallback: VALU cvt staging (ws too small)
#pragma unroll
            for (int jj = 0; jj < 4; ++jj) {
                const int p  = jj * NTHREADS + tid;   // 0..1023
                const int il = p >> 7;
                const int o  = p & 127;
                const float* src = cf + ((size_t)(it * IPB + il) * O_DIM + bn0 + o) * NDEG;
                const float4 w0 = reinterpret_cast<const float4*>(src)[0];
                const float4 w1 = reinterpret_cast<const float4*>(src)[1];
                union { s8v s; unsigned u[4]; } pk;
                pk.u[0] = pack2bf(w0.x, w0.y);
                pk.u[1] = pack2bf(w0.z, w0.w);
                pk.u[2] = pack2bf(w1.x, w1.y);
                pk.u[3] = pack2bf(w1.z, w1.w);
                *reinterpret_cast<s8v*>(&Ws[(il * BN + o) * NDEG]) = pk.s;
            }
        }

        // ---- A stage: x -> tanh -> Chebyshev-U -> bf16 -> LDS ----
        {
            const float4 xv = *reinterpret_cast<const float4*>(xp + it * IPB);
            const float vv[4] = {xv.x, xv.y, xv.z, xv.w};
#pragma unroll
            for (int j = 0; j < 4; ++j) {
                const float t  = fast_tanh(vv[j]);
                const float t2 = t + t;
                const float c1 = t2;
                const float c2 = t2 * c1 - 1.0f;
                const float c3 = t2 * c2 - c1;
                const float c4 = t2 * c3 - c2;
                const float c5 = t2 * c4 - c3;
                const float c6 = t2 * c5 - c4;
                const float c7 = t2 * c6 - c5;
                union { s8v s; unsigned u[4]; } pk;
                pk.u[0] = pack2bf(1.0f, c1);
                pk.u[1] = pack2bf(c2, c3);
                pk.u[2] = pack2bf(c4, c5);
                pk.u[3] = pack2bf(c6, c7);
                *reinterpret_cast<s8v*>(&As[ar * LSTR + (ai + j) * NDEG]) = pk.s;
            }
        }
        __syncthreads();

        // ---- compute: 2 k-chunks of 32, 4x4 of mfma 16x16x32 ----
#pragma unroll
        for (int kc = 0; kc < 2; ++kc) {
            s8v afr[4], bfr[4];
#pragma unroll
            for (int tm = 0; tm < 4; ++tm)
                afr[tm] = *reinterpret_cast<const s8v*>(
                    &As[(wr + tm * 16 + fm) * LSTR + kc * 32 + fq * 8]);
#pragma unroll
            for (int tn = 0; tn < 4; ++tn)
                bfr[tn] = *reinterpret_cast<const s8v*>(
                    &Ws[((kc * 4 + fq) * BN + wc + tn * 16 + fm) * NDEG]);
#pragma unroll
            for (int tm = 0; tm < 4; ++tm)
#pragma unroll
                for (int tn = 0; tn < 4; ++tn)
                    acc[tm][tn] = __builtin_amdgcn_mfma_f32_16x16x32_bf16(
                        afr[tm], bfr[tn], acc[tm][tn], 0, 0, 0);
        }
        __syncthreads();
    }

    // ---- epilogue: C/D col=lane&15, row=fq*4+reg ----
#pragma unroll
    for (int tm = 0; tm < 4; ++tm) {
#pragma unroll
        for (int tn = 0; tn < 4; ++tn) {
            const int row = bm0 + wr + tm * 16 + fq * 4;
            const int col = bn0 + wc + tn * 16 + fm;
#pragma unroll
            for (int r = 0; r < 4; ++r)
                out[(size_t)(row + r) * O_DIM + col] = acc[tm][tn][r];
        }
    }
}

extern "C" void kernel_launch(void* const* d_in, const int* in_sizes, int n_in,
                              void* d_out, int out_size, void* d_ws, size_t ws_size,
                              hipStream_t stream) {
    const float* x  = (const float*)d_in[0];
    const float* cf = (const float*)d_in[1];
    float* out = (float*)d_out;
    const int M = in_sizes[0] / I_DIM;            // 16384
    dim3 grid(O_DIM / BN, M / BM);                // (4, 128) = 512 blocks
    dim3 block(NTHREADS, 1, 1);

    if (ws_size >= (size_t)W_ELEMS * sizeof(u16)) {
        u16* wbf = (u16*)d_ws;
        cvt_w<<<W_ELEMS / 1024, 256, 0, stream>>>(cf, wbf);
        gegen_gemm<true><<<grid, block, 0, stream>>>(x, cf, wbf, out);
    } else {
        gegen_gemm<false><<<grid, block, 0, stream>>>(x, cf, nullptr, out);
    }
}